// Round 2
// baseline (134.385 us; speedup 1.0000x reference)
//
#include <hip/hip_runtime.h>
#include <hip/hip_bf16.h>

// Fused: out[b,i,o] = sum_e w3[o,e] * sum_j adj[b,i,j] * leaky(sum_f ef[b,i,j,f]*w4[e,f])
// ALL inputs/outputs are fp32 (reference dtypes). We convert ef/w4 to bf16
// in-kernel (RNE) and use mfma_f32_16x16x32_bf16 with fp32 accumulation;
// the test threshold (1.84 at max|ref|=92, i.e. 2% rel) allows bf16 compute.
//
// One block (4 waves, 256 thr) per row (b,i): 2048 blocks = 8 blocks/CU.
// Wave w handles j in [w*128, w*128+128) as 8 tiles of 16, K padded 16->32
// (B-frag k=16..31 is zero, so A's pad half is don't-care).

typedef __attribute__((ext_vector_type(8))) short bf16x8;   // 8 bf16 = 4 VGPRs
typedef __attribute__((ext_vector_type(4))) float f32x4;

constexpr int NN = 512;   // N
constexpr int NF = 16;    // edge features (K)
constexpr int NE = 64;    // embed dim
constexpr int WAVES = 4;
constexpr int JT = 16;                    // j per tile
constexpr int TPW = (NN / JT) / WAVES;    // 8 tiles per wave

__device__ __forceinline__ short f2bf(float x) {
    return (short)__builtin_bit_cast(unsigned short, __float2bfloat16(x));  // RNE
}

__global__ void __launch_bounds__(256, 4)
edge_embed_kernel(const float* __restrict__ ef,   // (B,N,N,16) fp32
                  const float* __restrict__ adj,  // (B,N,N)    fp32
                  const float* __restrict__ w4,   // (64,16)    fp32
                  const float* __restrict__ w3,   // (64,64)    fp32
                  float* __restrict__ out)        // (B,N,64)   fp32
{
    const int row  = blockIdx.x;          // b*N + i
    const int tid  = threadIdx.x;
    const int wave = tid >> 6;
    const int lane = tid & 63;
    const int m    = lane & 15;           // A-frag row / D col index
    const int quad = lane >> 4;           // k-half select (0,1) / D row group

    __shared__ float adjf[NN];
    __shared__ float partial[WAVES * NE];
    __shared__ float summed[NE];

    // ---- stage adj row into LDS (fp32, coalesced float2 per thread) ----
    {
        const float* ar = adj + (size_t)row * NN;
        float2 a2 = *(const float2*)(ar + 2 * tid);
        adjf[2 * tid]     = a2.x;
        adjf[2 * tid + 1] = a2.y;
    }

    // ---- B fragments: w4 e-groups of 16. w4 is (E,F) = B^T layout:
    // lane holds w4[g*16 + (lane&15)][quad*8 .. quad*8+7]; quads 2,3 = K-pad zeros.
    bf16x8 bfrag[4];
    #pragma unroll
    for (int g = 0; g < 4; ++g) {
        bf16x8 v = {0,0,0,0,0,0,0,0};
        if (quad < 2) {
            const float* p = w4 + ((g * 16 + m) * NF + quad * 8);
            #pragma unroll
            for (int j = 0; j < 8; ++j) v[j] = f2bf(p[j]);
        }
        bfrag[g] = v;
    }

    __syncthreads();

    const float* efr = ef + (size_t)row * NN * NF;
    const int j0 = wave * (TPW * JT);

    // fp32 load of this lane's A slice (32B = two float4); convert later.
    auto load_a_f32 = [&](int jt, float4& f0, float4& f1) {
        if (quad < 2) {
            const float* p = efr + ((size_t)(jt + m) * NF + quad * 8);
            f0 = *(const float4*)p;
            f1 = *(const float4*)(p + 4);
        }
    };
    auto cvt_a = [&](const float4& f0, const float4& f1) -> bf16x8 {
        bf16x8 v;
        v[0] = f2bf(f0.x); v[1] = f2bf(f0.y); v[2] = f2bf(f0.z); v[3] = f2bf(f0.w);
        v[4] = f2bf(f1.x); v[5] = f2bf(f1.y); v[6] = f2bf(f1.z); v[7] = f2bf(f1.w);
        return v;
    };

    float accg[4] = {0.f, 0.f, 0.f, 0.f};  // per-lane: e = g*16 + (lane&15)

    float4 c0 = {0,0,0,0}, c1 = {0,0,0,0};
    load_a_f32(j0, c0, c1);

    #pragma unroll
    for (int t = 0; t < TPW; ++t) {
        float4 n0 = {0,0,0,0}, n1 = {0,0,0,0};
        if (t + 1 < TPW) load_a_f32(j0 + (t + 1) * JT, n0, n1);   // prefetch

        const bf16x8 a_cur = cvt_a(c0, c1);

        const int jt = j0 + t * JT;
        // D rows this lane owns: jt + quad*4 + {0..3}  ->  matching adj values
        const float4 aj = *(const float4*)&adjf[jt + quad * 4];  // ds_read_b128, bcast
        const float ajr[4] = {aj.x, aj.y, aj.z, aj.w};

        const f32x4 zero = {0.f, 0.f, 0.f, 0.f};
        #pragma unroll
        for (int g = 0; g < 4; ++g) {
            f32x4 d = __builtin_amdgcn_mfma_f32_16x16x32_bf16(a_cur, bfrag[g], zero, 0, 0, 0);
            #pragma unroll
            for (int r = 0; r < 4; ++r) {
                float x = d[r];
                float v = fmaxf(x, 0.f) + 0.01f * fminf(x, 0.f);  // LeakyReLU
                accg[g] = fmaf(ajr[r], v, accg[g]);
            }
        }
        c0 = n0; c1 = n1;
    }

    // ---- reduce over quads (lanes sharing lane&15 hold disjoint j-rows) ----
    #pragma unroll
    for (int g = 0; g < 4; ++g) {
        accg[g] += __shfl_xor(accg[g], 16);
        accg[g] += __shfl_xor(accg[g], 32);
    }
    if (quad == 0) {
        #pragma unroll
        for (int g = 0; g < 4; ++g)
            partial[wave * NE + g * 16 + m] = accg[g];
    }
    __syncthreads();

    // ---- cross-wave reduce (all threads reach both barriers) ----
    if (tid < NE)
        summed[tid] = partial[tid] + partial[NE + tid]
                    + partial[2 * NE + tid] + partial[3 * NE + tid];
    __syncthreads();

    // ---- w3 projection + store: wave 0 only, output o = lane ----
    if (wave == 0) {
        const float* w3r = w3 + lane * NE;   // w3 is (O,E) row-major
        float r = 0.f;
        #pragma unroll
        for (int e = 0; e < NE; e += 4) {
            float4 wv = *(const float4*)(w3r + e);
            float4 sv = *(const float4*)&summed[e];
            r = fmaf(wv.x, sv.x, r);
            r = fmaf(wv.y, sv.y, r);
            r = fmaf(wv.z, sv.z, r);
            r = fmaf(wv.w, sv.w, r);
        }
        out[(size_t)row * NE + lane] = r;
    }
}

extern "C" void kernel_launch(void* const* d_in, const int* in_sizes, int n_in,
                              void* d_out, int out_size, void* d_ws, size_t ws_size,
                              hipStream_t stream) {
    const float* ef  = (const float*)d_in[0];
    const float* adj = (const float*)d_in[1];
    const float* w4  = (const float*)d_in[2];
    const float* w3  = (const float*)d_in[3];
    float* out = (float*)d_out;

    const int rows = in_sizes[1] / NN;    // B*N = adj_elems / N = 2048
    edge_embed_kernel<<<dim3(rows), dim3(256), 0, stream>>>(ef, adj, w4, w3, out);
}

// Round 3
// 108.248 us; speedup vs baseline: 1.2415x; 1.2415x over previous
//
#include <hip/hip_runtime.h>
#include <hip/hip_bf16.h>

// Fused: out[b,i,o] = sum_e w3[o,e] * sum_j adj[b,i,j] * leaky(sum_f ef[b,i,j,f]*w4[e,f])
// fp32 in/out; ef/w4 converted to bf16 in-kernel, mfma_f32_16x16x32_bf16, fp32 acc.
//
// R3 change vs R2: latency-bound fix. All 8 j-tiles' ef loads are issued
// up-front (16x dwordx4 in flight per wave, FIFO-consumed with fine vmcnt),
// and adj staging became per-wave (no pre-loop __syncthreads -> no vmcnt(0)
// drain of the in-flight ef loads).

typedef __attribute__((ext_vector_type(8))) short bf16x8;   // 8 bf16 = 4 VGPRs
typedef __attribute__((ext_vector_type(4))) float f32x4;

constexpr int NN = 512;   // N
constexpr int NF = 16;    // edge features (K)
constexpr int NE = 64;    // embed dim
constexpr int WAVES = 4;
constexpr int JT = 16;                    // j per tile
constexpr int TPW = (NN / JT) / WAVES;    // 8 tiles per wave

__device__ __forceinline__ short f2bf(float x) {
    return (short)__builtin_bit_cast(unsigned short, __float2bfloat16(x));  // RNE
}

__global__ void __launch_bounds__(256, 4)
edge_embed_kernel(const float* __restrict__ ef,   // (B,N,N,16) fp32
                  const float* __restrict__ adj,  // (B,N,N)    fp32
                  const float* __restrict__ w4,   // (64,16)    fp32
                  const float* __restrict__ w3,   // (64,64)    fp32
                  float* __restrict__ out)        // (B,N,64)   fp32
{
    const int row  = blockIdx.x;          // b*N + i
    const int tid  = threadIdx.x;
    const int wave = tid >> 6;
    const int lane = tid & 63;
    const int m    = lane & 15;           // A-frag row / D col index
    const int quad = lane >> 4;           // k-group / D row group

    __shared__ float adjf[NN];            // per-wave 128-float slices
    __shared__ float partial[WAVES * NE];
    __shared__ float summed[NE];

    const int j0 = wave * (TPW * JT);

    // ---- phase 1: small loads (adj slice + w4), consumed before ef issue ----
    // adj: each wave stages ONLY its own [j0, j0+128) slice; reads below stay
    // inside that slice, so no __syncthreads is needed (wave-internal lgkmcnt).
    const float2 a2 = *(const float2*)(adj + (size_t)row * NN + j0 + 2 * lane);

    float4 wf[8];
    #pragma unroll
    for (int g = 0; g < 4; ++g) {
        wf[2 * g]     = make_float4(0.f, 0.f, 0.f, 0.f);
        wf[2 * g + 1] = make_float4(0.f, 0.f, 0.f, 0.f);
        if (quad < 2) {
            const float* p = w4 + ((g * 16 + m) * NF + quad * 8);
            wf[2 * g]     = *(const float4*)p;
            wf[2 * g + 1] = *(const float4*)(p + 4);
        }
    }

    adjf[j0 + 2 * lane]     = a2.x;
    adjf[j0 + 2 * lane + 1] = a2.y;

    // B fragments: w4 is (E,F) = B^T layout. lane holds
    // w4[g*16 + m][quad*8 .. +8); quads 2,3 = K-pad zeros (k=16..31 of B).
    bf16x8 bfrag[4];
    #pragma unroll
    for (int g = 0; g < 4; ++g) {
        bf16x8 v;
        v[0] = f2bf(wf[2*g].x);   v[1] = f2bf(wf[2*g].y);
        v[2] = f2bf(wf[2*g].z);   v[3] = f2bf(wf[2*g].w);
        v[4] = f2bf(wf[2*g+1].x); v[5] = f2bf(wf[2*g+1].y);
        v[6] = f2bf(wf[2*g+1].z); v[7] = f2bf(wf[2*g+1].w);
        bfrag[g] = v;
    }

    // ---- phase 2: issue ALL 8 tiles' ef loads back-to-back (deep MLP) ----
    // Zero-init so quad>=2 lanes carry 0 (their k=16..31 hits zero B rows,
    // and garbage there could be NaN: NaN*0 = NaN).
    const float* efr = ef + (size_t)row * NN * NF;
    float4 pre[2 * TPW];
    #pragma unroll
    for (int t = 0; t < TPW; ++t) {
        pre[2 * t]     = make_float4(0.f, 0.f, 0.f, 0.f);
        pre[2 * t + 1] = make_float4(0.f, 0.f, 0.f, 0.f);
        if (quad < 2) {
            const float* p = efr + ((size_t)(j0 + t * JT + m) * NF + quad * 8);
            pre[2 * t]     = *(const float4*)p;
            pre[2 * t + 1] = *(const float4*)(p + 4);
        }
    }

    // ---- phase 3: consume tiles in FIFO order ----
    float accg[4] = {0.f, 0.f, 0.f, 0.f};  // per-lane: e = g*16 + m

    #pragma unroll
    for (int t = 0; t < TPW; ++t) {
        bf16x8 a;
        a[0] = f2bf(pre[2*t].x);   a[1] = f2bf(pre[2*t].y);
        a[2] = f2bf(pre[2*t].z);   a[3] = f2bf(pre[2*t].w);
        a[4] = f2bf(pre[2*t+1].x); a[5] = f2bf(pre[2*t+1].y);
        a[6] = f2bf(pre[2*t+1].z); a[7] = f2bf(pre[2*t+1].w);

        const int jt = j0 + t * JT;
        // D rows this lane owns: jt + quad*4 + {0..3}
        const float4 aj = *(const float4*)&adjf[jt + quad * 4];
        const float ajr[4] = {aj.x, aj.y, aj.z, aj.w};

        const f32x4 zero = {0.f, 0.f, 0.f, 0.f};
        #pragma unroll
        for (int g = 0; g < 4; ++g) {
            f32x4 d = __builtin_amdgcn_mfma_f32_16x16x32_bf16(a, bfrag[g], zero, 0, 0, 0);
            #pragma unroll
            for (int r = 0; r < 4; ++r) {
                float x = d[r];
                float v = fmaxf(x, 0.f) + 0.01f * fminf(x, 0.f);  // LeakyReLU
                accg[g] = fmaf(ajr[r], v, accg[g]);
            }
        }
    }

    // ---- reduce over quads (lanes sharing m hold disjoint j-rows) ----
    #pragma unroll
    for (int g = 0; g < 4; ++g) {
        accg[g] += __shfl_xor(accg[g], 16);
        accg[g] += __shfl_xor(accg[g], 32);
    }
    if (quad == 0) {
        #pragma unroll
        for (int g = 0; g < 4; ++g)
            partial[wave * NE + g * 16 + m] = accg[g];
    }
    __syncthreads();

    // ---- cross-wave reduce (all threads reach both barriers) ----
    if (tid < NE)
        summed[tid] = partial[tid] + partial[NE + tid]
                    + partial[2 * NE + tid] + partial[3 * NE + tid];
    __syncthreads();

    // ---- w3 projection + store: wave 0 only, output o = lane ----
    if (wave == 0) {
        const float* w3r = w3 + lane * NE;   // w3 is (O,E) row-major
        float r = 0.f;
        #pragma unroll
        for (int e = 0; e < NE; e += 4) {
            float4 wv = *(const float4*)(w3r + e);
            float4 sv = *(const float4*)&summed[e];
            r = fmaf(wv.x, sv.x, r);
            r = fmaf(wv.y, sv.y, r);
            r = fmaf(wv.z, sv.z, r);
            r = fmaf(wv.w, sv.w, r);
        }
        out[(size_t)row * NE + lane] = r;
    }
}

extern "C" void kernel_launch(void* const* d_in, const int* in_sizes, int n_in,
                              void* d_out, int out_size, void* d_ws, size_t ws_size,
                              hipStream_t stream) {
    const float* ef  = (const float*)d_in[0];
    const float* adj = (const float*)d_in[1];
    const float* w4  = (const float*)d_in[2];
    const float* w3  = (const float*)d_in[3];
    float* out = (float*)d_out;

    const int rows = in_sizes[1] / NN;    // B*N = 2048
    edge_embed_kernel<<<dim3(rows), dim3(256), 0, stream>>>(ef, adj, w4, w3, out);
}

// Round 4
// 102.928 us; speedup vs baseline: 1.3056x; 1.0517x over previous
//
#include <hip/hip_runtime.h>
#include <hip/hip_bf16.h>

// Fused: out[b,i,o] = sum_e w3[o,e] * sum_j adj[b,i,j] * leaky(sum_f ef[b,i,j,f]*w4[e,f])
// fp32 in/out; ef/w4 -> bf16 in-kernel, mfma_f32_16x16x32_bf16, fp32 acc.
//
// R4 change vs R3: full-lane tile loads. Each 16x16 ef tile is 1KB contiguous;
// one wave64 dwordx4 (lane*16B) loads it whole. Lane l holds row l>>2,
// floats [(l&3)*4,+4). MFMA A-frags are assembled via 4 ds_bpermute per tile
// from packed-bf16 dwords. Halves VMEM instrs (16->8/wave) and prefetch
// VGPRs (64->32), eliminating spill pressure while keeping all 8 tiles'
// loads in flight (issued in consumption order: adj, w4, ef t=0..7).

typedef __attribute__((ext_vector_type(8))) short bf16x8;   // 8 bf16 = 4 VGPRs
typedef __attribute__((ext_vector_type(4))) float f32x4;
typedef __attribute__((ext_vector_type(4))) int   i32x4;

constexpr int NN = 512;   // N
constexpr int NF = 16;    // edge features (K)
constexpr int NE = 64;    // embed dim
constexpr int WAVES = 4;
constexpr int JT = 16;                    // j per tile
constexpr int TPW = (NN / JT) / WAVES;    // 8 tiles per wave

__device__ __forceinline__ unsigned short f2bfu(float x) {
    return __builtin_bit_cast(unsigned short, __float2bfloat16(x));  // RNE
}
__device__ __forceinline__ int pack2(float lo, float hi) {
    return (int)((unsigned)f2bfu(lo) | ((unsigned)f2bfu(hi) << 16));
}

__global__ void __launch_bounds__(256, 4)
edge_embed_kernel(const float* __restrict__ ef,   // (B,N,N,16) fp32
                  const float* __restrict__ adj,  // (B,N,N)    fp32
                  const float* __restrict__ w4,   // (64,16)    fp32
                  const float* __restrict__ w3,   // (64,64)    fp32
                  float* __restrict__ out)        // (B,N,64)   fp32
{
    const int row  = blockIdx.x;          // b*N + i
    const int tid  = threadIdx.x;
    const int wave = tid >> 6;
    const int lane = tid & 63;
    const int m    = lane & 15;           // A-frag row / D col index
    const int quad = lane >> 4;           // D row group; quads 0,1 = real K

    __shared__ float adjf[NN];            // per-wave 128-float slices
    __shared__ float partial[WAVES * NE];
    __shared__ float summed[NE];

    const int j0 = wave * (TPW * JT);

    // ---- issue order == consumption order: adj, w4, then ef tiles ----
    const float2 a2 = *(const float2*)(adj + (size_t)row * NN + j0 + 2 * lane);

    float4 wf[8];
    #pragma unroll
    for (int g = 0; g < 4; ++g) {
        wf[2 * g]     = make_float4(0.f, 0.f, 0.f, 0.f);
        wf[2 * g + 1] = make_float4(0.f, 0.f, 0.f, 0.f);
        if (quad < 2) {
            const float* p = w4 + ((g * 16 + m) * NF + quad * 8);
            wf[2 * g]     = *(const float4*)p;
            wf[2 * g + 1] = *(const float4*)(p + 4);
        }
    }

    // ef: ALL 8 tiles issued back-to-back, full 64 lanes, 1KB per instr.
    const float* efr = ef + (size_t)row * NN * NF;
    float4 pre[TPW];
    #pragma unroll
    for (int t = 0; t < TPW; ++t)
        pre[t] = *(const float4*)(efr + (size_t)(j0 + t * JT) * NF + lane * 4);

    // ---- consume adj (per-wave LDS slice; wave-internal, no barrier) ----
    adjf[j0 + 2 * lane]     = a2.x;
    adjf[j0 + 2 * lane + 1] = a2.y;

    // ---- consume w4 -> B fragments (w4 is (E,F) = B^T layout) ----
    // lane holds w4[g*16+m][quad*8..+8); quads 2,3 = K-pad zeros (k=16..31).
    bf16x8 bfrag[4];
    #pragma unroll
    for (int g = 0; g < 4; ++g) {
        i32x4 v = {pack2(wf[2*g].x,   wf[2*g].y),
                   pack2(wf[2*g].z,   wf[2*g].w),
                   pack2(wf[2*g+1].x, wf[2*g+1].y),
                   pack2(wf[2*g+1].z, wf[2*g+1].w)};
        bfrag[g] = __builtin_bit_cast(bf16x8, v);
    }

    // ---- consume ef tiles in FIFO order ----
    // A-frag lane (quad,m) needs row m floats [8*(quad&1), +8) =
    // packed dwords of source lanes m*4 + (quad&1)*2 and +1.
    // Quads 2,3 mirror quads 0,1: finite values x zero B rows = 0.
    const int src0 = m * 4 + (quad & 1) * 2;
    float accg[4] = {0.f, 0.f, 0.f, 0.f};  // per-lane: e = g*16 + m

    #pragma unroll
    for (int t = 0; t < TPW; ++t) {
        const int u0 = pack2(pre[t].x, pre[t].y);   // own floats 0,1
        const int u1 = pack2(pre[t].z, pre[t].w);   // own floats 2,3

        i32x4 ai = {__shfl(u0, src0),     __shfl(u1, src0),
                    __shfl(u0, src0 + 1), __shfl(u1, src0 + 1)};
        const bf16x8 a = __builtin_bit_cast(bf16x8, ai);

        const int jt = j0 + t * JT;
        // D rows this lane owns: jt + quad*4 + {0..3}
        const float4 aj = *(const float4*)&adjf[jt + quad * 4];
        const float ajr[4] = {aj.x, aj.y, aj.z, aj.w};

        const f32x4 zero = {0.f, 0.f, 0.f, 0.f};
        #pragma unroll
        for (int g = 0; g < 4; ++g) {
            f32x4 d = __builtin_amdgcn_mfma_f32_16x16x32_bf16(a, bfrag[g], zero, 0, 0, 0);
            #pragma unroll
            for (int r = 0; r < 4; ++r) {
                float x = d[r];
                float v = fmaf(0.01f, fminf(x, 0.f), fmaxf(x, 0.f));  // LeakyReLU
                accg[g] = fmaf(ajr[r], v, accg[g]);
            }
        }
    }

    // ---- reduce over quads (lanes sharing m hold disjoint j-rows) ----
    #pragma unroll
    for (int g = 0; g < 4; ++g) {
        accg[g] += __shfl_xor(accg[g], 16);
        accg[g] += __shfl_xor(accg[g], 32);
    }
    if (quad == 0) {
        #pragma unroll
        for (int g = 0; g < 4; ++g)
            partial[wave * NE + g * 16 + m] = accg[g];
    }
    __syncthreads();

    // ---- cross-wave reduce (all threads reach both barriers) ----
    if (tid < NE)
        summed[tid] = partial[tid] + partial[NE + tid]
                    + partial[2 * NE + tid] + partial[3 * NE + tid];
    __syncthreads();

    // ---- w3 projection + store: wave 0 only, output o = lane ----
    if (wave == 0) {
        const float* w3r = w3 + lane * NE;   // w3 is (O,E) row-major
        float r = 0.f;
        #pragma unroll
        for (int e = 0; e < NE; e += 4) {
            float4 wv = *(const float4*)(w3r + e);
            float4 sv = *(const float4*)&summed[e];
            r = fmaf(wv.x, sv.x, r);
            r = fmaf(wv.y, sv.y, r);
            r = fmaf(wv.z, sv.z, r);
            r = fmaf(wv.w, sv.w, r);
        }
        out[(size_t)row * NE + lane] = r;
    }
}

extern "C" void kernel_launch(void* const* d_in, const int* in_sizes, int n_in,
                              void* d_out, int out_size, void* d_ws, size_t ws_size,
                              hipStream_t stream) {
    const float* ef  = (const float*)d_in[0];
    const float* adj = (const float*)d_in[1];
    const float* w4  = (const float*)d_in[2];
    const float* w3  = (const float*)d_in[3];
    float* out = (float*)d_out;

    const int rows = in_sizes[1] / NN;    // B*N = 2048
    edge_embed_kernel<<<dim3(rows), dim3(256), 0, stream>>>(ef, adj, w4, w3, out);
}